// Round 8
// baseline (137.946 us; speedup 1.0000x reference)
//
#include <hip/hip_runtime.h>
#include <hip/hip_bf16.h>

// Problem constants
#define B_    4
#define T_    4096
#define D_    1024
#define NH_   16
#define NS_   64
#define HD_   64
#define ALPHA_ 0.1f
#define M_    (B_*T_)        // 16384 rows
#define N_    (NH_*NS_)      // 1024 cols (head*slot)
#define NCH_  128            // time chunks for the suffix scan
#define CHUNK_ (T_/NCH_)     // 32

typedef __attribute__((ext_vector_type(8))) short short8v;
typedef __attribute__((ext_vector_type(4))) float f32x4;
typedef _Float16 f16x8 __attribute__((ext_vector_type(8)));

__device__ inline unsigned short f2bf(float x) {
    unsigned u = __float_as_uint(x);
    unsigned r = u + 0x7FFF + ((u >> 16) & 1);   // RNE
    return (unsigned short)(r >> 16);
}

// ---------------------------------------------------------------------------
// Kernel 0: H fp32 -> bf16.
__global__ __launch_bounds__(256)
void k_h2bf(const float* __restrict__ H, unsigned short* __restrict__ Hb) {
    int idx = blockIdx.x * 256 + threadIdx.x;         // unit = 8 floats
    const int stride = 2048 * 256;
    #pragma unroll
    for (int it = 0; it < 4; ++it) {
        int e = (idx + it * stride) * 8;
        float4 f0 = *(const float4*)&H[e];
        float4 f1 = *(const float4*)&H[e + 4];
        __hip_bfloat162 q0 = __float22bfloat162_rn(make_float2(f0.x, f0.y));
        __hip_bfloat162 q1 = __float22bfloat162_rn(make_float2(f0.z, f0.w));
        __hip_bfloat162 q2 = __float22bfloat162_rn(make_float2(f1.x, f1.y));
        __hip_bfloat162 q3 = __float22bfloat162_rn(make_float2(f1.z, f1.w));
        uint4 u = {*(unsigned*)&q0, *(unsigned*)&q1, *(unsigned*)&q2, *(unsigned*)&q3};
        *(uint4*)&Hb[e] = u;
    }
}

// ---------------------------------------------------------------------------
// Kernel 1 (v2): fold W_tok into prototypes, emit bf16. Block = (head h,
// 64-col m-range): stages 64x64 slices of proto and W in LDS; W read ONCE.
__global__ __launch_bounds__(256)
void k_protoproj(const float* __restrict__ proto,
                 const float* __restrict__ W,
                 unsigned short* __restrict__ Pb) {
    int bid = blockIdx.x;            // 256
    int h = bid >> 4, mr = bid & 15;
    int m0 = mr * 64;
    __shared__ float pl[64][68];
    __shared__ float Wl[64][68];
    int tid = threadIdx.x;
    int rr = tid >> 2, cg = (tid & 3) * 16;
    #pragma unroll
    for (int i = 0; i < 4; ++i)
        *(float4*)&pl[rr][cg + i * 4] =
            *(const float4*)&proto[rr * D_ + h * 64 + cg + i * 4];
    #pragma unroll
    for (int i = 0; i < 4; ++i)
        *(float4*)&Wl[rr][cg + i * 4] =
            *(const float4*)&W[(h * 64 + rr) * D_ + m0 + cg + i * 4];
    __syncthreads();
    int s = tid & 63, mg = (tid >> 6) * 16;
    float acc[16] = {};
    for (int k = 0; k < 64; ++k) {
        float pv = pl[s][k];
        #pragma unroll
        for (int i = 0; i < 16; ++i) acc[i] += pv * Wl[k][mg + i];
    }
    unsigned short ob[16];
    #pragma unroll
    for (int i = 0; i < 16; ++i) ob[i] = f2bf(0.125f * acc[i]);
    unsigned short* dst = &Pb[(size_t)(h * 64 + s) * D_ + m0 + mg];
    *(uint4*)dst       = *(uint4*)&ob[0];
    *(uint4*)(dst + 8) = *(uint4*)&ob[8];
}

// ---------------------------------------------------------------------------
// Kernel 2 (v3): pure bf16 MFMA GEMM -> raw scores in f16.
// 128x128 tile, BK=32, 4 waves, 16x16x32 MFMA. T3 minimum-2-phase:
// double-buffered LDS; per K-step: issue next tile's 4 global_load_lds,
// ds_read+MFMA current, ONE barrier (its vmcnt(0) drain lands after a full
// compute phase of overlap). Buffer indices compile-time via 2x unroll.
__global__ __launch_bounds__(256)
void k_gemm(const unsigned short* __restrict__ Ab,   // Hb [M_, D_] bf16
            const unsigned short* __restrict__ Bp,   // Pb [N_, D_] bf16
            _Float16* __restrict__ C) {              // scores [M_, N_] f16
    __shared__ unsigned short As[2][128 * 32];
    __shared__ unsigned short Bs[2][128 * 32];
    int tid = threadIdx.x;
    int bid = blockIdx.x;
    int wgid = (bid & 7) * 128 + (bid >> 3);
    int bm = wgid >> 3, bn = wgid & 7;
    int m0 = bm * 128, n0 = bn * 128;
    int l = tid & 63, wv = tid >> 6;
    int wr = wv >> 1, wc = wv & 1;
    int lr = l & 15, lk = l >> 4;

    int srow = tid >> 2;
    int skof = (tid & 3) * 8;
    const unsigned short* Ap = Ab + (size_t)(m0 + srow) * D_ + skof;
    const unsigned short* Bq = Bp + (size_t)(n0 + srow) * D_ + skof;

    f32x4 acc[4][4];
    #pragma unroll
    for (int i = 0; i < 4; ++i)
        #pragma unroll
        for (int j = 0; j < 4; ++j) acc[i][j] = (f32x4){0.f, 0.f, 0.f, 0.f};

    const int aoff = (wr * 64 + lr) * 32 + lk * 8;
    const int boff = (wc * 64 + lr) * 32 + lk * 8;

#define GSTAGE(BUF, K0)                                                         \
    __builtin_amdgcn_global_load_lds(                                           \
        (const __attribute__((address_space(1))) void*)(Ap + (K0)),             \
        (__attribute__((address_space(3))) void*)(&As[BUF][tid * 8]), 16, 0, 0);\
    __builtin_amdgcn_global_load_lds(                                           \
        (const __attribute__((address_space(1))) void*)(Ap + (size_t)64 * D_ + (K0)), \
        (__attribute__((address_space(3))) void*)(&As[BUF][tid * 8 + 64 * 32]), 16, 0, 0); \
    __builtin_amdgcn_global_load_lds(                                           \
        (const __attribute__((address_space(1))) void*)(Bq + (K0)),             \
        (__attribute__((address_space(3))) void*)(&Bs[BUF][tid * 8]), 16, 0, 0);\
    __builtin_amdgcn_global_load_lds(                                           \
        (const __attribute__((address_space(1))) void*)(Bq + (size_t)64 * D_ + (K0)), \
        (__attribute__((address_space(3))) void*)(&Bs[BUF][tid * 8 + 64 * 32]), 16, 0, 0);

#define KSTEP(BUFR)                                                             \
    {                                                                           \
        short8v af[4], bf[4];                                                   \
        _Pragma("unroll")                                                       \
        for (int m = 0; m < 4; ++m)                                             \
            af[m] = *(const short8v*)&As[BUFR][aoff + m * 16 * 32];             \
        _Pragma("unroll")                                                       \
        for (int n = 0; n < 4; ++n)                                             \
            bf[n] = *(const short8v*)&Bs[BUFR][boff + n * 16 * 32];             \
        _Pragma("unroll")                                                       \
        for (int m = 0; m < 4; ++m)                                             \
            _Pragma("unroll")                                                   \
            for (int n = 0; n < 4; ++n)                                         \
                acc[m][n] = __builtin_amdgcn_mfma_f32_16x16x32_bf16(            \
                    af[m], bf[n], acc[m][n], 0, 0, 0);                          \
    }

    GSTAGE(0, 0)
    __syncthreads();
    for (int t = 0; t < 30; t += 2) {
        GSTAGE(1, (t + 1) * 32)       // prefetch odd tile into buf1
        KSTEP(0)                      // compute even tile from buf0
        __syncthreads();
        GSTAGE(0, (t + 2) * 32)       // prefetch even tile into buf0
        KSTEP(1)                      // compute odd tile from buf1
        __syncthreads();
    }
    // t = 30: prefetch last tile (31) into buf1, compute tile 30 from buf0
    GSTAGE(1, 31 * 32)
    KSTEP(0)
    __syncthreads();
    KSTEP(1)                          // final tile, no prefetch
#undef GSTAGE
#undef KSTEP

    int crow = m0 + wr * 64 + lk * 4;
    int ccol = n0 + wc * 64 + lr;
    #pragma unroll
    for (int m = 0; m < 4; ++m)
        #pragma unroll
        for (int n = 0; n < 4; ++n)
            #pragma unroll
            for (int j = 0; j < 4; ++j)
                C[(size_t)(crow + m * 16 + j) * N_ + ccol + n * 16] =
                    (_Float16)acc[m][n][j];
}

// ---------------------------------------------------------------------------
// Kernel 3 (v2): per-chunk g-products, vectorized (unchanged from R7).
__global__ __launch_bounds__(256)
void k_cp(const _Float16* __restrict__ S, float* __restrict__ cp) {
    int bid = blockIdx.x;                 // 256
    int bh = bid >> 2, qt = bid & 3;
    int b = bh >> 4, h = bh & 15;
    int w = threadIdx.x >> 6, l = threadIdx.x & 63;
    int sg = (l & 7) * 8;
    for (int k = 0; k < 8; ++k) {
        int c = qt * 32 + w * 8 + k;
        int tb = c * CHUNK_;
        float pg[8] = {1.f, 1.f, 1.f, 1.f, 1.f, 1.f, 1.f, 1.f};
        #pragma unroll
        for (int i = 0; i < 4; ++i) {
            int t = tb + (l >> 3) + i * 8;
            f16x8 sv = *(const f16x8*)(S + (size_t)(b * T_ + t) * N_ + h * 64 + sg);
            float e[8]; float ps = 0.f;
            #pragma unroll
            for (int j = 0; j < 8; ++j) { e[j] = __expf((float)sv[j]); ps += e[j]; }
            ps += __shfl_xor(ps, 1);
            ps += __shfl_xor(ps, 2);
            ps += __shfl_xor(ps, 4);
            float inv = 1.f / ps;
            #pragma unroll
            for (int j = 0; j < 8; ++j) pg[j] *= 1.f - ALPHA_ * (e[j] * inv);
        }
        #pragma unroll
        for (int off = 8; off <= 32; off <<= 1)
            #pragma unroll
            for (int j = 0; j < 8; ++j) pg[j] *= __shfl_xor(pg[j], off);
        if ((l >> 3) == 0) {
            int base = (bh * NCH_ + c) * 64 + l * 8;
            *(float4*)&cp[base]     = (float4){pg[0], pg[1], pg[2], pg[3]};
            *(float4*)&cp[base + 4] = (float4){pg[4], pg[5], pg[6], pg[7]};
        }
    }
}

// ---------------------------------------------------------------------------
// Kernel 4: softmax + weff walk + MFMA output accumulation (unchanged).
__global__ __launch_bounds__(256)
void k_out_mfma(const _Float16* __restrict__ S,       // raw scores
                const unsigned short* __restrict__ Hb,// bf16 H
                const float* __restrict__ cp,
                float* __restrict__ out) {
    int bx = blockIdx.x;                  // 1024
    int cf = bx & 15, h = (bx >> 4) & 15, b = bx >> 8;
    __shared__ _Float16 ws16[64][72];           // softmaxed w
    __shared__ unsigned short tmp[64][72];      // staged Hb rows
    __shared__ float ppl[4][64];                // per-16-row g partial products
    __shared__ _Float16 wt[8 * 64 * 8];         // w_eff^T subtiled [tg][s][8]
    __shared__ _Float16 hd[8 * 64 * 8];         // H^T    subtiled [tg][d][8]
    int tid = threadIdx.x;
    int lr0 = tid >> 3, lc = (tid & 7) * 8;     // load role: rows lr0, lr0+32
    int s = tid & 63, q = tid >> 6;             // walk/transpose role
    int fr = s & 15, fk = s >> 4, wv = q;       // mfma role

    // --- prologue: global-suffix values su[it] = prod_{c > cf*8+it} cp[c][s]
    int cbase = (b * NH_ + h) * NCH_;
    float su[8];
    {
        float P = 1.f;
        for (int c = NCH_ - 1; c >= cf * 8 + 8; --c)
            P *= cp[(cbase + c) * 64 + s];
        su[7] = P;
        #pragma unroll
        for (int it = 6; it >= 0; --it)
            su[it] = su[it + 1] * cp[(cbase + cf * 8 + it + 1) * 64 + s];
    }

    f32x4 acc[4];
    #pragma unroll
    for (int n = 0; n < 4; ++n) acc[n] = (f32x4){0.f, 0.f, 0.f, 0.f};

    for (int it = 0; it < 4; ++it) {
        int tb = cf * 256 + it * 64;
        size_t r0 = (size_t)(b * T_ + tb + lr0) * N_ + h * 64 + lc;
        size_t r1 = r0 + (size_t)32 * N_;
        f16x8  sv0 = *(const f16x8*)(S + r0);
        f16x8  sv1 = *(const f16x8*)(S + r1);
        short8v hv0 = *(const short8v*)(Hb + r0);
        short8v hv1 = *(const short8v*)(Hb + r1);
        // softmax per row (8-lane group, no max-sub; |score| small)
        _Float16 w0[8], w1[8];
        {
            float e[8]; float ps = 0.f;
            #pragma unroll
            for (int j = 0; j < 8; ++j) { e[j] = __expf((float)sv0[j]); ps += e[j]; }
            ps += __shfl_xor(ps, 1); ps += __shfl_xor(ps, 2); ps += __shfl_xor(ps, 4);
            float inv = 1.f / ps;
            #pragma unroll
            for (int j = 0; j < 8; ++j) w0[j] = (_Float16)(e[j] * inv);
        }
        {
            float e[8]; float ps = 0.f;
            #pragma unroll
            for (int j = 0; j < 8; ++j) { e[j] = __expf((float)sv1[j]); ps += e[j]; }
            ps += __shfl_xor(ps, 1); ps += __shfl_xor(ps, 2); ps += __shfl_xor(ps, 4);
            float inv = 1.f / ps;
            #pragma unroll
            for (int j = 0; j < 8; ++j) w1[j] = (_Float16)(e[j] * inv);
        }
        __syncthreads();                  // A: prior iter's LDS reads done
        *(f16x8*)&ws16[lr0][lc]      = *(f16x8*)w0;
        *(f16x8*)&ws16[lr0 + 32][lc] = *(f16x8*)w1;
        *(short8v*)&tmp[lr0][lc]      = hv0;
        *(short8v*)&tmp[lr0 + 32][lc] = hv1;
        __syncthreads();                  // B: ws16 + tmp visible
        // ppl: partial product of g over this thread's 16 rows
        {
            float pp = 1.f;
            #pragma unroll
            for (int r = 0; r < 16; ++r)
                pp *= 1.f - ALPHA_ * (float)ws16[q * 16 + r][s];
            ppl[q][s] = pp;
        }
        // transpose Hb: thread (q,s): tg = q and q+4, cvt bf16 -> f16
        #pragma unroll
        for (int x = 0; x < 2; ++x) {
            int tg = q + x * 4;
            _Float16 hreg[8];
            #pragma unroll
            for (int r = 0; r < 8; ++r) {
                unsigned short ub = tmp[tg * 8 + r][s];
                hreg[r] = (_Float16)__uint_as_float((unsigned)ub << 16);
            }
            *(f16x8*)&hd[(tg * 64 + s) * 8] = *(f16x8*)hreg;
        }
        __syncthreads();                  // C: ppl + hd visible
        // walk: rows q*16..q*16+15 backward; chunk split at q<2 | q>=2
        {
            float suf = (q >= 2) ? su[it * 2 + 1] : su[it * 2];
            if (q == 2) suf *= ppl[3][s];
            if (q == 0) suf *= ppl[1][s];
            _Float16 wr16[16];
            #pragma unroll
            for (int r = 15; r >= 0; --r) {
                float wv_ = (float)ws16[q * 16 + r][s];
                wr16[r] = (_Float16)(ALPHA_ * wv_ * suf);
                suf *= 1.f - ALPHA_ * wv_;
            }
            *(f16x8*)&wt[((2 * q)     * 64 + s) * 8] = *(f16x8*)&wr16[0];
            *(f16x8*)&wt[((2 * q + 1) * 64 + s) * 8] = *(f16x8*)&wr16[8];
        }
        __syncthreads();                  // D: wt visible
        // MFMA: wave wv -> s-block wv*16, all 64 d; K=64 = 2 k-steps
        #pragma unroll
        for (int kk = 0; kk < 2; ++kk) {
            int tg = kk * 4 + fk;
            f16x8 af = *(const f16x8*)&wt[(tg * 64 + wv * 16 + fr) * 8];
            #pragma unroll
            for (int n = 0; n < 4; ++n) {
                f16x8 bf = *(const f16x8*)&hd[(tg * 64 + n * 16 + fr) * 8];
                acc[n] = __builtin_amdgcn_mfma_f32_16x16x32_f16(
                    af, bf, acc[n], 0, 0, 0);
            }
        }
    }
    // D layout: row (s-dim) = fk*4 + j, col (d-dim) = fr
    #pragma unroll
    for (int n = 0; n < 4; ++n)
        #pragma unroll
        for (int j = 0; j < 4; ++j)
            atomicAdd(&out[((b * NS_ + wv * 16 + fk * 4 + j) * NH_ + h) * HD_
                           + n * 16 + fr],
                      acc[n][j]);
}

// ---------------------------------------------------------------------------
extern "C" void kernel_launch(void* const* d_in, const int* in_sizes, int n_in,
                              void* d_out, int out_size, void* d_ws, size_t ws_size,
                              hipStream_t stream) {
    const float* H     = (const float*)d_in[0];
    const float* proto = (const float*)d_in[1];
    const float* W     = (const float*)d_in[2];
    float* out = (float*)d_out;
    char*  ws  = (char*)d_ws;

    _Float16*       S  = (_Float16*)ws;                                  // 32 MB
    unsigned short* Hb = (unsigned short*)(ws + (size_t)M_ * N_ * 2);    // 32 MB
    unsigned short* Pb = (unsigned short*)(ws + (size_t)M_ * N_ * 2
                                              + (size_t)M_ * D_ * 2);    // 2 MB
    float* cp = (float*)((char*)Pb + (size_t)N_ * D_ * 2);               // 2 MB

    hipMemsetAsync(d_out, 0, (size_t)out_size * sizeof(float), stream);

    k_h2bf      <<<2048,              256, 0, stream>>>(H, Hb);
    k_protoproj <<<256,               256, 0, stream>>>(proto, W, Pb);
    k_gemm      <<<(M_/128)*(N_/128), 256, 0, stream>>>(Hb, Pb, S);
    k_cp        <<<256,               256, 0, stream>>>(S, cp);
    k_out_mfma  <<<B_*NH_*16,         256, 0, stream>>>(S, Hb, cp, out);
}

// Round 9
// 125.561 us; speedup vs baseline: 1.0986x; 1.0986x over previous
//
#include <hip/hip_runtime.h>
#include <hip/hip_bf16.h>

// Problem constants
#define B_    4
#define T_    4096
#define D_    1024
#define NH_   16
#define NS_   64
#define HD_   64
#define ALPHA_ 0.1f
#define M_    (B_*T_)        // 16384 rows
#define N_    (NH_*NS_)      // 1024 cols (head*slot)
#define NCH_  128            // time chunks for the suffix scan
#define CHUNK_ (T_/NCH_)     // 32

typedef __attribute__((ext_vector_type(8))) short short8v;
typedef __attribute__((ext_vector_type(4))) float f32x4;
typedef _Float16 f16x8 __attribute__((ext_vector_type(8)));

__device__ inline unsigned short f2bf(float x) {
    unsigned u = __float_as_uint(x);
    unsigned r = u + 0x7FFF + ((u >> 16) & 1);   // RNE
    return (unsigned short)(r >> 16);
}

// ---------------------------------------------------------------------------
// Kernel 0: H fp32 -> bf16.
__global__ __launch_bounds__(256)
void k_h2bf(const float* __restrict__ H, unsigned short* __restrict__ Hb) {
    int idx = blockIdx.x * 256 + threadIdx.x;         // unit = 8 floats
    const int stride = 2048 * 256;
    #pragma unroll
    for (int it = 0; it < 4; ++it) {
        int e = (idx + it * stride) * 8;
        float4 f0 = *(const float4*)&H[e];
        float4 f1 = *(const float4*)&H[e + 4];
        __hip_bfloat162 q0 = __float22bfloat162_rn(make_float2(f0.x, f0.y));
        __hip_bfloat162 q1 = __float22bfloat162_rn(make_float2(f0.z, f0.w));
        __hip_bfloat162 q2 = __float22bfloat162_rn(make_float2(f1.x, f1.y));
        __hip_bfloat162 q3 = __float22bfloat162_rn(make_float2(f1.z, f1.w));
        uint4 u = {*(unsigned*)&q0, *(unsigned*)&q1, *(unsigned*)&q2, *(unsigned*)&q3};
        *(uint4*)&Hb[e] = u;
    }
}

// ---------------------------------------------------------------------------
// Kernel 1 (v2): fold W_tok into prototypes, emit bf16 (unchanged).
__global__ __launch_bounds__(256)
void k_protoproj(const float* __restrict__ proto,
                 const float* __restrict__ W,
                 unsigned short* __restrict__ Pb) {
    int bid = blockIdx.x;            // 256
    int h = bid >> 4, mr = bid & 15;
    int m0 = mr * 64;
    __shared__ float pl[64][68];
    __shared__ float Wl[64][68];
    int tid = threadIdx.x;
    int rr = tid >> 2, cg = (tid & 3) * 16;
    #pragma unroll
    for (int i = 0; i < 4; ++i)
        *(float4*)&pl[rr][cg + i * 4] =
            *(const float4*)&proto[rr * D_ + h * 64 + cg + i * 4];
    #pragma unroll
    for (int i = 0; i < 4; ++i)
        *(float4*)&Wl[rr][cg + i * 4] =
            *(const float4*)&W[(h * 64 + rr) * D_ + m0 + cg + i * 4];
    __syncthreads();
    int s = tid & 63, mg = (tid >> 6) * 16;
    float acc[16] = {};
    for (int k = 0; k < 64; ++k) {
        float pv = pl[s][k];
        #pragma unroll
        for (int i = 0; i < 16; ++i) acc[i] += pv * Wl[k][mg + i];
    }
    unsigned short ob[16];
    #pragma unroll
    for (int i = 0; i < 16; ++i) ob[i] = f2bf(0.125f * acc[i]);
    unsigned short* dst = &Pb[(size_t)(h * 64 + s) * D_ + m0 + mg];
    *(uint4*)dst       = *(uint4*)&ob[0];
    *(uint4*)(dst + 8) = *(uint4*)&ob[8];
}

// ---------------------------------------------------------------------------
// Kernel 2 (v4): pure bf16 MFMA GEMM -> raw scores in f16.
// 128x128 tile, BK=64 single-buffered: halves barrier-drain pairs (32 vs 64)
// with 32 MFMA amortizing each. LDS rows are 128B -> T2 XOR swizzle
// (16B-group ^= row&7) applied as inverse-swizzled GLOBAL source (linear
// gload_lds dest) + same XOR on frag reads. K-order per acc unchanged.
__global__ __launch_bounds__(256)
void k_gemm(const unsigned short* __restrict__ Ab,   // Hb [M_, D_] bf16
            const unsigned short* __restrict__ Bp,   // Pb [N_, D_] bf16
            _Float16* __restrict__ C) {              // scores [M_, N_] f16
    __shared__ unsigned short As[128 * 64];   // 16 KB
    __shared__ unsigned short Bs[128 * 64];   // 16 KB
    int tid = threadIdx.x;
    int bid = blockIdx.x;
    int wgid = (bid & 7) * 128 + (bid >> 3);
    int bm = wgid >> 3, bn = wgid & 7;
    int m0 = bm * 128, n0 = bn * 128;
    int l = tid & 63, wv = tid >> 6;
    int wr = wv >> 1, wc = wv & 1;
    int lr = l & 15, lk = l >> 4;

    // staging: per issue i: row = (tid>>3) + i*32, 16B-group = tid&7.
    // swizzled source group = (tid&7) ^ (row&7); (row&7) == (tid>>3)&7.
    int srow = tid >> 3;                  // 0..31
    int skgs = (tid & 7) ^ (srow & 7);    // pre-swizzled global 16B group
    const unsigned short* Ap = Ab + (size_t)(m0 + srow) * D_ + skgs * 8;
    const unsigned short* Bq = Bp + (size_t)(n0 + srow) * D_ + skgs * 8;

    f32x4 acc[4][4];
    #pragma unroll
    for (int i = 0; i < 4; ++i)
        #pragma unroll
        for (int j = 0; j < 4; ++j) acc[i][j] = (f32x4){0.f, 0.f, 0.f, 0.f};

    for (int k0 = 0; k0 < D_; k0 += 64) {
        __syncthreads();   // previous tile's MFMA reads complete
        #pragma unroll
        for (int i = 0; i < 4; ++i) {
            __builtin_amdgcn_global_load_lds(
                (const __attribute__((address_space(1))) void*)(Ap + (size_t)(i * 32) * D_ + k0),
                (__attribute__((address_space(3))) void*)(&As[tid * 8 + i * 2048]), 16, 0, 0);
            __builtin_amdgcn_global_load_lds(
                (const __attribute__((address_space(1))) void*)(Bq + (size_t)(i * 32) * D_ + k0),
                (__attribute__((address_space(3))) void*)(&Bs[tid * 8 + i * 2048]), 16, 0, 0);
        }
        __syncthreads();   // staging visible
        // frag reads: row = w*64 + f*16 + lr, k-16B-group g = kk*4+lk, g ^= lr&7
        #pragma unroll
        for (int kk = 0; kk < 2; ++kk) {
            short8v af[4], bf[4];
            int gp = ((kk * 4 + lk) ^ (lr & 7)) * 8;
            #pragma unroll
            for (int m = 0; m < 4; ++m)
                af[m] = *(const short8v*)&As[(wr * 64 + m * 16 + lr) * 64 + gp];
            #pragma unroll
            for (int n = 0; n < 4; ++n)
                bf[n] = *(const short8v*)&Bs[(wc * 64 + n * 16 + lr) * 64 + gp];
            #pragma unroll
            for (int m = 0; m < 4; ++m)
                #pragma unroll
                for (int n = 0; n < 4; ++n)
                    acc[m][n] = __builtin_amdgcn_mfma_f32_16x16x32_bf16(
                        af[m], bf[n], acc[m][n], 0, 0, 0);
        }
    }

    int crow = m0 + wr * 64 + lk * 4;
    int ccol = n0 + wc * 64 + lr;
    #pragma unroll
    for (int m = 0; m < 4; ++m)
        #pragma unroll
        for (int n = 0; n < 4; ++n)
            #pragma unroll
            for (int j = 0; j < 4; ++j)
                C[(size_t)(crow + m * 16 + j) * N_ + ccol + n * 16] =
                    (_Float16)acc[m][n][j];
}

// ---------------------------------------------------------------------------
// Kernel 3 (v2): per-chunk g-products, vectorized (unchanged).
__global__ __launch_bounds__(256)
void k_cp(const _Float16* __restrict__ S, float* __restrict__ cp) {
    int bid = blockIdx.x;                 // 256
    int bh = bid >> 2, qt = bid & 3;
    int b = bh >> 4, h = bh & 15;
    int w = threadIdx.x >> 6, l = threadIdx.x & 63;
    int sg = (l & 7) * 8;
    for (int k = 0; k < 8; ++k) {
        int c = qt * 32 + w * 8 + k;
        int tb = c * CHUNK_;
        float pg[8] = {1.f, 1.f, 1.f, 1.f, 1.f, 1.f, 1.f, 1.f};
        #pragma unroll
        for (int i = 0; i < 4; ++i) {
            int t = tb + (l >> 3) + i * 8;
            f16x8 sv = *(const f16x8*)(S + (size_t)(b * T_ + t) * N_ + h * 64 + sg);
            float e[8]; float ps = 0.f;
            #pragma unroll
            for (int j = 0; j < 8; ++j) { e[j] = __expf((float)sv[j]); ps += e[j]; }
            ps += __shfl_xor(ps, 1);
            ps += __shfl_xor(ps, 2);
            ps += __shfl_xor(ps, 4);
            float inv = 1.f / ps;
            #pragma unroll
            for (int j = 0; j < 8; ++j) pg[j] *= 1.f - ALPHA_ * (e[j] * inv);
        }
        #pragma unroll
        for (int off = 8; off <= 32; off <<= 1)
            #pragma unroll
            for (int j = 0; j < 8; ++j) pg[j] *= __shfl_xor(pg[j], off);
        if ((l >> 3) == 0) {
            int base = (bh * NCH_ + c) * 64 + l * 8;
            *(float4*)&cp[base]     = (float4){pg[0], pg[1], pg[2], pg[3]};
            *(float4*)&cp[base + 4] = (float4){pg[4], pg[5], pg[6], pg[7]};
        }
    }
}

// ---------------------------------------------------------------------------
// Kernel 4 (v2): softmax + weff walk + MFMA output accumulation, with T14
// async-stage: iteration it+1's S/Hb loads issue right after the LDS write
// (registers free), hiding HBM latency under ppl/transpose/walk/MFMA.
__global__ __launch_bounds__(256)
void k_out_mfma(const _Float16* __restrict__ S,       // raw scores
                const unsigned short* __restrict__ Hb,// bf16 H
                const float* __restrict__ cp,
                float* __restrict__ out) {
    int bx = blockIdx.x;                  // 1024
    int cf = bx & 15, h = (bx >> 4) & 15, b = bx >> 8;
    __shared__ _Float16 ws16[64][72];           // softmaxed w
    __shared__ unsigned short tmp[64][72];      // staged Hb rows
    __shared__ float ppl[4][64];                // per-16-row g partial products
    __shared__ _Float16 wt[8 * 64 * 8];         // w_eff^T subtiled [tg][s][8]
    __shared__ _Float16 hd[8 * 64 * 8];         // H^T    subtiled [tg][d][8]
    int tid = threadIdx.x;
    int lr0 = tid >> 3, lc = (tid & 7) * 8;     // load role: rows lr0, lr0+32
    int s = tid & 63, q = tid >> 6;             // walk/transpose role
    int fr = s & 15, fk = s >> 4, wv = q;       // mfma role

    // T14: issue it=0 loads before the cp prologue so they overlap it
    size_t rr0 = (size_t)(b * T_ + cf * 256 + lr0) * N_ + h * 64 + lc;
    f16x8  sv0 = *(const f16x8*)(S + rr0);
    f16x8  sv1 = *(const f16x8*)(S + rr0 + (size_t)32 * N_);
    short8v hv0 = *(const short8v*)(Hb + rr0);
    short8v hv1 = *(const short8v*)(Hb + rr0 + (size_t)32 * N_);

    // prologue: global-suffix values su[it] = prod_{c > cf*8+it} cp[c][s]
    int cbase = (b * NH_ + h) * NCH_;
    float su[8];
    {
        float P = 1.f;
        for (int c = NCH_ - 1; c >= cf * 8 + 8; --c)
            P *= cp[(cbase + c) * 64 + s];
        su[7] = P;
        #pragma unroll
        for (int it = 6; it >= 0; --it)
            su[it] = su[it + 1] * cp[(cbase + cf * 8 + it + 1) * 64 + s];
    }

    f32x4 acc[4];
    #pragma unroll
    for (int n = 0; n < 4; ++n) acc[n] = (f32x4){0.f, 0.f, 0.f, 0.f};

    for (int it = 0; it < 4; ++it) {
        // softmax per row (8-lane group, no max-sub; |score| small)
        _Float16 w0[8], w1[8];
        {
            float e[8]; float ps = 0.f;
            #pragma unroll
            for (int j = 0; j < 8; ++j) { e[j] = __expf((float)sv0[j]); ps += e[j]; }
            ps += __shfl_xor(ps, 1); ps += __shfl_xor(ps, 2); ps += __shfl_xor(ps, 4);
            float inv = 1.f / ps;
            #pragma unroll
            for (int j = 0; j < 8; ++j) w0[j] = (_Float16)(e[j] * inv);
        }
        {
            float e[8]; float ps = 0.f;
            #pragma unroll
            for (int j = 0; j < 8; ++j) { e[j] = __expf((float)sv1[j]); ps += e[j]; }
            ps += __shfl_xor(ps, 1); ps += __shfl_xor(ps, 2); ps += __shfl_xor(ps, 4);
            float inv = 1.f / ps;
            #pragma unroll
            for (int j = 0; j < 8; ++j) w1[j] = (_Float16)(e[j] * inv);
        }
        __syncthreads();                  // A: prior iter's LDS reads done
        *(f16x8*)&ws16[lr0][lc]      = *(f16x8*)w0;
        *(f16x8*)&ws16[lr0 + 32][lc] = *(f16x8*)w1;
        *(short8v*)&tmp[lr0][lc]      = hv0;
        *(short8v*)&tmp[lr0 + 32][lc] = hv1;
        __syncthreads();                  // B: ws16 + tmp visible
        // T14: issue next iteration's loads now (regs free, latency hidden)
        if (it < 3) {
            size_t rn = rr0 + (size_t)((it + 1) * 64) * N_;
            sv0 = *(const f16x8*)(S + rn);
            sv1 = *(const f16x8*)(S + rn + (size_t)32 * N_);
            hv0 = *(const short8v*)(Hb + rn);
            hv1 = *(const short8v*)(Hb + rn + (size_t)32 * N_);
        }
        // ppl: partial product of g over this thread's 16 rows
        {
            float pp = 1.f;
            #pragma unroll
            for (int r = 0; r < 16; ++r)
                pp *= 1.f - ALPHA_ * (float)ws16[q * 16 + r][s];
            ppl[q][s] = pp;
        }
        // transpose Hb: thread (q,s): tg = q and q+4, cvt bf16 -> f16
        #pragma unroll
        for (int x = 0; x < 2; ++x) {
            int tg = q + x * 4;
            _Float16 hreg[8];
            #pragma unroll
            for (int r = 0; r < 8; ++r) {
                unsigned short ub = tmp[tg * 8 + r][s];
                hreg[r] = (_Float16)__uint_as_float((unsigned)ub << 16);
            }
            *(f16x8*)&hd[(tg * 64 + s) * 8] = *(f16x8*)hreg;
        }
        __syncthreads();                  // C: ppl + hd visible
        // walk: rows q*16..q*16+15 backward; chunk split at q<2 | q>=2
        {
            float suf = (q >= 2) ? su[it * 2 + 1] : su[it * 2];
            if (q == 2) suf *= ppl[3][s];
            if (q == 0) suf *= ppl[1][s];
            _Float16 wr16[16];
            #pragma unroll
            for (int r = 15; r >= 0; --r) {
                float wv_ = (float)ws16[q * 16 + r][s];
                wr16[r] = (_Float16)(ALPHA_ * wv_ * suf);
                suf *= 1.f - ALPHA_ * wv_;
            }
            *(f16x8*)&wt[((2 * q)     * 64 + s) * 8] = *(f16x8*)&wr16[0];
            *(f16x8*)&wt[((2 * q + 1) * 64 + s) * 8] = *(f16x8*)&wr16[8];
        }
        __syncthreads();                  // D: wt visible
        // MFMA: wave wv -> s-block wv*16, all 64 d; K=64 = 2 k-steps
        #pragma unroll
        for (int kk = 0; kk < 2; ++kk) {
            int tg = kk * 4 + fk;
            f16x8 af = *(const f16x8*)&wt[(tg * 64 + wv * 16 + fr) * 8];
            #pragma unroll
            for (int n = 0; n < 4; ++n) {
                f16x8 bf = *(const f16x8*)&hd[(tg * 64 + n * 16 + fr) * 8];
                acc[n] = __builtin_amdgcn_mfma_f32_16x16x32_f16(
                    af, bf, acc[n], 0, 0, 0);
            }
        }
    }
    // D layout: row (s-dim) = fk*4 + j, col (d-dim) = fr
    #pragma unroll
    for (int n = 0; n < 4; ++n)
        #pragma unroll
        for (int j = 0; j < 4; ++j)
            atomicAdd(&out[((b * NS_ + wv * 16 + fk * 4 + j) * NH_ + h) * HD_
                           + n * 16 + fr],
                      acc[n][j]);
}

// ---------------------------------------------------------------------------
extern "C" void kernel_launch(void* const* d_in, const int* in_sizes, int n_in,
                              void* d_out, int out_size, void* d_ws, size_t ws_size,
                              hipStream_t stream) {
    const float* H     = (const float*)d_in[0];
    const float* proto = (const float*)d_in[1];
    const float* W     = (const float*)d_in[2];
    float* out = (float*)d_out;
    char*  ws  = (char*)d_ws;

    _Float16*       S  = (_Float16*)ws;                                  // 32 MB
    unsigned short* Hb = (unsigned short*)(ws + (size_t)M_ * N_ * 2);    // 32 MB
    unsigned short* Pb = (unsigned short*)(ws + (size_t)M_ * N_ * 2
                                              + (size_t)M_ * D_ * 2);    // 2 MB
    float* cp = (float*)((char*)Pb + (size_t)N_ * D_ * 2);               // 2 MB

    hipMemsetAsync(d_out, 0, (size_t)out_size * sizeof(float), stream);

    k_h2bf      <<<2048,              256, 0, stream>>>(H, Hb);
    k_protoproj <<<256,               256, 0, stream>>>(proto, W, Pb);
    k_gemm      <<<(M_/128)*(N_/128), 256, 0, stream>>>(Hb, Pb, S);
    k_cp        <<<256,               256, 0, stream>>>(S, cp);
    k_out_mfma  <<<B_*NH_*16,         256, 0, stream>>>(S, Hb, cp, out);
}

// Round 10
// 107.920 us; speedup vs baseline: 1.2782x; 1.1635x over previous
//
#include <hip/hip_runtime.h>
#include <hip/hip_bf16.h>

// Problem constants
#define B_    4
#define T_    4096
#define D_    1024
#define NH_   16
#define NS_   64
#define HD_   64
#define ALPHA_ 0.1f
#define M_    (B_*T_)        // 16384 rows
#define N_    (NH_*NS_)      // 1024 cols (head*slot)
#define NCH_  128            // time chunks for the suffix scan
#define CHUNK_ (T_/NCH_)     // 32

typedef __attribute__((ext_vector_type(8))) short short8v;
typedef __attribute__((ext_vector_type(4))) float f32x4;
typedef _Float16 f16x8 __attribute__((ext_vector_type(8)));

__device__ inline unsigned short f2bf(float x) {
    unsigned u = __float_as_uint(x);
    unsigned r = u + 0x7FFF + ((u >> 16) & 1);   // RNE
    return (unsigned short)(r >> 16);
}

// ---------------------------------------------------------------------------
// Kernel 0: H fp32 -> bf16.
__global__ __launch_bounds__(256)
void k_h2bf(const float* __restrict__ H, unsigned short* __restrict__ Hb) {
    int idx = blockIdx.x * 256 + threadIdx.x;         // unit = 8 floats
    const int stride = 2048 * 256;
    #pragma unroll
    for (int it = 0; it < 4; ++it) {
        int e = (idx + it * stride) * 8;
        float4 f0 = *(const float4*)&H[e];
        float4 f1 = *(const float4*)&H[e + 4];
        __hip_bfloat162 q0 = __float22bfloat162_rn(make_float2(f0.x, f0.y));
        __hip_bfloat162 q1 = __float22bfloat162_rn(make_float2(f0.z, f0.w));
        __hip_bfloat162 q2 = __float22bfloat162_rn(make_float2(f1.x, f1.y));
        __hip_bfloat162 q3 = __float22bfloat162_rn(make_float2(f1.z, f1.w));
        uint4 u = {*(unsigned*)&q0, *(unsigned*)&q1, *(unsigned*)&q2, *(unsigned*)&q3};
        *(uint4*)&Hb[e] = u;
    }
}

// ---------------------------------------------------------------------------
// Kernel 1 (v2): fold W_tok into prototypes, emit bf16 (unchanged).
__global__ __launch_bounds__(256)
void k_protoproj(const float* __restrict__ proto,
                 const float* __restrict__ W,
                 unsigned short* __restrict__ Pb) {
    int bid = blockIdx.x;            // 256
    int h = bid >> 4, mr = bid & 15;
    int m0 = mr * 64;
    __shared__ float pl[64][68];
    __shared__ float Wl[64][68];
    int tid = threadIdx.x;
    int rr = tid >> 2, cg = (tid & 3) * 16;
    #pragma unroll
    for (int i = 0; i < 4; ++i)
        *(float4*)&pl[rr][cg + i * 4] =
            *(const float4*)&proto[rr * D_ + h * 64 + cg + i * 4];
    #pragma unroll
    for (int i = 0; i < 4; ++i)
        *(float4*)&Wl[rr][cg + i * 4] =
            *(const float4*)&W[(h * 64 + rr) * D_ + m0 + cg + i * 4];
    __syncthreads();
    int s = tid & 63, mg = (tid >> 6) * 16;
    float acc[16] = {};
    for (int k = 0; k < 64; ++k) {
        float pv = pl[s][k];
        #pragma unroll
        for (int i = 0; i < 16; ++i) acc[i] += pv * Wl[k][mg + i];
    }
    unsigned short ob[16];
    #pragma unroll
    for (int i = 0; i < 16; ++i) ob[i] = f2bf(0.125f * acc[i]);
    unsigned short* dst = &Pb[(size_t)(h * 64 + s) * D_ + m0 + mg];
    *(uint4*)dst       = *(uint4*)&ob[0];
    *(uint4*)(dst + 8) = *(uint4*)&ob[8];
}

// ---------------------------------------------------------------------------
// Kernel 2 (v4): pure bf16 MFMA GEMM -> raw scores in f16 (unchanged from R9:
// BK=64 single-buffered, both-sides T2 swizzle via pre-swizzled global src).
__global__ __launch_bounds__(256)
void k_gemm(const unsigned short* __restrict__ Ab,   // Hb [M_, D_] bf16
            const unsigned short* __restrict__ Bp,   // Pb [N_, D_] bf16
            _Float16* __restrict__ C) {              // scores [M_, N_] f16
    __shared__ unsigned short As[128 * 64];   // 16 KB
    __shared__ unsigned short Bs[128 * 64];   // 16 KB
    int tid = threadIdx.x;
    int bid = blockIdx.x;
    int wgid = (bid & 7) * 128 + (bid >> 3);
    int bm = wgid >> 3, bn = wgid & 7;
    int m0 = bm * 128, n0 = bn * 128;
    int l = tid & 63, wv = tid >> 6;
    int wr = wv >> 1, wc = wv & 1;
    int lr = l & 15, lk = l >> 4;

    int srow = tid >> 3;                  // 0..31
    int skgs = (tid & 7) ^ (srow & 7);    // pre-swizzled global 16B group
    const unsigned short* Ap = Ab + (size_t)(m0 + srow) * D_ + skgs * 8;
    const unsigned short* Bq = Bp + (size_t)(n0 + srow) * D_ + skgs * 8;

    f32x4 acc[4][4];
    #pragma unroll
    for (int i = 0; i < 4; ++i)
        #pragma unroll
        for (int j = 0; j < 4; ++j) acc[i][j] = (f32x4){0.f, 0.f, 0.f, 0.f};

    for (int k0 = 0; k0 < D_; k0 += 64) {
        __syncthreads();   // previous tile's MFMA reads complete
        #pragma unroll
        for (int i = 0; i < 4; ++i) {
            __builtin_amdgcn_global_load_lds(
                (const __attribute__((address_space(1))) void*)(Ap + (size_t)(i * 32) * D_ + k0),
                (__attribute__((address_space(3))) void*)(&As[tid * 8 + i * 2048]), 16, 0, 0);
            __builtin_amdgcn_global_load_lds(
                (const __attribute__((address_space(1))) void*)(Bq + (size_t)(i * 32) * D_ + k0),
                (__attribute__((address_space(3))) void*)(&Bs[tid * 8 + i * 2048]), 16, 0, 0);
        }
        __syncthreads();   // staging visible
        #pragma unroll
        for (int kk = 0; kk < 2; ++kk) {
            short8v af[4], bf[4];
            int gp = ((kk * 4 + lk) ^ (lr & 7)) * 8;
            #pragma unroll
            for (int m = 0; m < 4; ++m)
                af[m] = *(const short8v*)&As[(wr * 64 + m * 16 + lr) * 64 + gp];
            #pragma unroll
            for (int n = 0; n < 4; ++n)
                bf[n] = *(const short8v*)&Bs[(wc * 64 + n * 16 + lr) * 64 + gp];
            #pragma unroll
            for (int m = 0; m < 4; ++m)
                #pragma unroll
                for (int n = 0; n < 4; ++n)
                    acc[m][n] = __builtin_amdgcn_mfma_f32_16x16x32_bf16(
                        af[m], bf[n], acc[m][n], 0, 0, 0);
        }
    }

    int crow = m0 + wr * 64 + lk * 4;
    int ccol = n0 + wc * 64 + lr;
    #pragma unroll
    for (int m = 0; m < 4; ++m)
        #pragma unroll
        for (int n = 0; n < 4; ++n)
            #pragma unroll
            for (int j = 0; j < 4; ++j)
                C[(size_t)(crow + m * 16 + j) * N_ + ccol + n * 16] =
                    (_Float16)acc[m][n][j];
}

// ---------------------------------------------------------------------------
// Kernel 3 (v2): per-chunk g-products, vectorized (unchanged).
__global__ __launch_bounds__(256)
void k_cp(const _Float16* __restrict__ S, float* __restrict__ cp) {
    int bid = blockIdx.x;                 // 256
    int bh = bid >> 2, qt = bid & 3;
    int b = bh >> 4, h = bh & 15;
    int w = threadIdx.x >> 6, l = threadIdx.x & 63;
    int sg = (l & 7) * 8;
    for (int k = 0; k < 8; ++k) {
        int c = qt * 32 + w * 8 + k;
        int tb = c * CHUNK_;
        float pg[8] = {1.f, 1.f, 1.f, 1.f, 1.f, 1.f, 1.f, 1.f};
        #pragma unroll
        for (int i = 0; i < 4; ++i) {
            int t = tb + (l >> 3) + i * 8;
            f16x8 sv = *(const f16x8*)(S + (size_t)(b * T_ + t) * N_ + h * 64 + sg);
            float e[8]; float ps = 0.f;
            #pragma unroll
            for (int j = 0; j < 8; ++j) { e[j] = __expf((float)sv[j]); ps += e[j]; }
            ps += __shfl_xor(ps, 1);
            ps += __shfl_xor(ps, 2);
            ps += __shfl_xor(ps, 4);
            float inv = 1.f / ps;
            #pragma unroll
            for (int j = 0; j < 8; ++j) pg[j] *= 1.f - ALPHA_ * (e[j] * inv);
        }
        #pragma unroll
        for (int off = 8; off <= 32; off <<= 1)
            #pragma unroll
            for (int j = 0; j < 8; ++j) pg[j] *= __shfl_xor(pg[j], off);
        if ((l >> 3) == 0) {
            int base = (bh * NCH_ + c) * 64 + l * 8;
            *(float4*)&cp[base]     = (float4){pg[0], pg[1], pg[2], pg[3]};
            *(float4*)&cp[base + 4] = (float4){pg[4], pg[5], pg[6], pg[7]};
        }
    }
}

// ---------------------------------------------------------------------------
// Kernel 3b (new): PARALLEL cross-chunk exclusive suffix scan.
// Block = one (b,h); cp[128][64] tile in LDS; 4 segment partials + 32-step
// backward walk per thread. Replaces k_out's serial 60-120-load prologue.
__global__ __launch_bounds__(256)
void k_scan(const float* __restrict__ cp, float* __restrict__ csuf) {
    int bh = blockIdx.x;                  // 64
    __shared__ float buf[128][64];        // 32 KB
    __shared__ float segp[4][64];
    int tid = threadIdx.x;
    #pragma unroll
    for (int i = 0; i < 8; ++i) {
        int e = tid * 4 + i * 1024;
        int c = e >> 6, sc = e & 63;
        *(float4*)&buf[c][sc] = *(const float4*)&cp[(bh * NCH_ + c) * 64 + sc];
    }
    __syncthreads();
    int s = tid & 63, seg = tid >> 6;
    float pp = 1.f;
    #pragma unroll
    for (int r = 0; r < 32; ++r) pp *= buf[seg * 32 + r][s];
    segp[seg][s] = pp;
    __syncthreads();
    float suf = 1.f;
    if (seg <= 2) suf *= segp[3][s];
    if (seg <= 1) suf *= segp[2][s];
    if (seg == 0) suf *= segp[1][s];
    #pragma unroll
    for (int r = 31; r >= 0; --r) {
        int c = seg * 32 + r;
        csuf[(bh * NCH_ + c) * 64 + s] = suf;   // EXCLUSIVE suffix
        suf *= buf[c][s];
    }
}

// ---------------------------------------------------------------------------
// Kernel 4 (v3): softmax + weff walk + MFMA output accumulation.
// Changes vs R9: prologue = 8 coalesced csuf loads (serial chain removed);
// barrier A dropped (redundant with D: MFMA only reads wt/hd, so post-D
// writes to ws16/tmp are already ordered against all prior readers).
__global__ __launch_bounds__(256)
void k_out_mfma(const _Float16* __restrict__ S,       // raw scores
                const unsigned short* __restrict__ Hb,// bf16 H
                const float* __restrict__ csuf,
                float* __restrict__ out) {
    int bx = blockIdx.x;                  // 1024
    int cf = bx & 15, h = (bx >> 4) & 15, b = bx >> 8;
    __shared__ _Float16 ws16[64][72];           // softmaxed w
    __shared__ unsigned short tmp[64][72];      // staged Hb rows
    __shared__ float ppl[4][64];                // per-16-row g partial products
    __shared__ _Float16 wt[8 * 64 * 8];         // w_eff^T subtiled [tg][s][8]
    __shared__ _Float16 hd[8 * 64 * 8];         // H^T    subtiled [tg][d][8]
    int tid = threadIdx.x;
    int lr0 = tid >> 3, lc = (tid & 7) * 8;     // load role: rows lr0, lr0+32
    int s = tid & 63, q = tid >> 6;             // walk/transpose role
    int fr = s & 15, fk = s >> 4, wv = q;       // mfma role

    // T14: issue it=0 loads first so they overlap the csuf loads
    size_t rr0 = (size_t)(b * T_ + cf * 256 + lr0) * N_ + h * 64 + lc;
    f16x8  sv0 = *(const f16x8*)(S + rr0);
    f16x8  sv1 = *(const f16x8*)(S + rr0 + (size_t)32 * N_);
    short8v hv0 = *(const short8v*)(Hb + rr0);
    short8v hv1 = *(const short8v*)(Hb + rr0 + (size_t)32 * N_);

    // prologue: su[k] = prod_{c > cf*8+k} cp[c][s] = csuf[cf*8+k][s]
    int cbase = (b * NH_ + h) * NCH_ + cf * 8;
    float su[8];
    #pragma unroll
    for (int k = 0; k < 8; ++k)
        su[k] = csuf[(cbase + k) * 64 + s];

    f32x4 acc[4];
    #pragma unroll
    for (int n = 0; n < 4; ++n) acc[n] = (f32x4){0.f, 0.f, 0.f, 0.f};

    for (int it = 0; it < 4; ++it) {
        // softmax per row (8-lane group, no max-sub; |score| small)
        _Float16 w0[8], w1[8];
        {
            float e[8]; float ps = 0.f;
            #pragma unroll
            for (int j = 0; j < 8; ++j) { e[j] = __expf((float)sv0[j]); ps += e[j]; }
            ps += __shfl_xor(ps, 1); ps += __shfl_xor(ps, 2); ps += __shfl_xor(ps, 4);
            float inv = 1.f / ps;
            #pragma unroll
            for (int j = 0; j < 8; ++j) w0[j] = (_Float16)(e[j] * inv);
        }
        {
            float e[8]; float ps = 0.f;
            #pragma unroll
            for (int j = 0; j < 8; ++j) { e[j] = __expf((float)sv1[j]); ps += e[j]; }
            ps += __shfl_xor(ps, 1); ps += __shfl_xor(ps, 2); ps += __shfl_xor(ps, 4);
            float inv = 1.f / ps;
            #pragma unroll
            for (int j = 0; j < 8; ++j) w1[j] = (_Float16)(e[j] * inv);
        }
        // (barrier A removed: prior iter's barrier D already ordered all
        //  ws16/tmp readers; MFMA between D and here reads only wt/hd)
        *(f16x8*)&ws16[lr0][lc]      = *(f16x8*)w0;
        *(f16x8*)&ws16[lr0 + 32][lc] = *(f16x8*)w1;
        *(short8v*)&tmp[lr0][lc]      = hv0;
        *(short8v*)&tmp[lr0 + 32][lc] = hv1;
        __syncthreads();                  // B: ws16 + tmp visible
        // T14: issue next iteration's loads now (regs free, latency hidden)
        if (it < 3) {
            size_t rn = rr0 + (size_t)((it + 1) * 64) * N_;
            sv0 = *(const f16x8*)(S + rn);
            sv1 = *(const f16x8*)(S + rn + (size_t)32 * N_);
            hv0 = *(const short8v*)(Hb + rn);
            hv1 = *(const short8v*)(Hb + rn + (size_t)32 * N_);
        }
        // ppl: partial product of g over this thread's 16 rows
        {
            float pp = 1.f;
            #pragma unroll
            for (int r = 0; r < 16; ++r)
                pp *= 1.f - ALPHA_ * (float)ws16[q * 16 + r][s];
            ppl[q][s] = pp;
        }
        // transpose Hb: thread (q,s): tg = q and q+4, cvt bf16 -> f16
        #pragma unroll
        for (int x = 0; x < 2; ++x) {
            int tg = q + x * 4;
            _Float16 hreg[8];
            #pragma unroll
            for (int r = 0; r < 8; ++r) {
                unsigned short ub = tmp[tg * 8 + r][s];
                hreg[r] = (_Float16)__uint_as_float((unsigned)ub << 16);
            }
            *(f16x8*)&hd[(tg * 64 + s) * 8] = *(f16x8*)hreg;
        }
        __syncthreads();                  // C: ppl + hd visible
        // walk: rows q*16..q*16+15 backward; chunk split at q<2 | q>=2
        {
            float suf = (q >= 2) ? su[it * 2 + 1] : su[it * 2];
            if (q == 2) suf *= ppl[3][s];
            if (q == 0) suf *= ppl[1][s];
            _Float16 wr16[16];
            #pragma unroll
            for (int r = 15; r >= 0; --r) {
                float wv_ = (float)ws16[q * 16 + r][s];
                wr16[r] = (_Float16)(ALPHA_ * wv_ * suf);
                suf *= 1.f - ALPHA_ * wv_;
            }
            *(f16x8*)&wt[((2 * q)     * 64 + s) * 8] = *(f16x8*)&wr16[0];
            *(f16x8*)&wt[((2 * q + 1) * 64 + s) * 8] = *(f16x8*)&wr16[8];
        }
        __syncthreads();                  // D: wt visible
        // MFMA: wave wv -> s-block wv*16, all 64 d; K=64 = 2 k-steps
        #pragma unroll
        for (int kk = 0; kk < 2; ++kk) {
            int tg = kk * 4 + fk;
            f16x8 af = *(const f16x8*)&wt[(tg * 64 + wv * 16 + fr) * 8];
            #pragma unroll
            for (int n = 0; n < 4; ++n) {
                f16x8 bf = *(const f16x8*)&hd[(tg * 64 + n * 16 + fr) * 8];
                acc[n] = __builtin_amdgcn_mfma_f32_16x16x32_f16(
                    af, bf, acc[n], 0, 0, 0);
            }
        }
    }
    // D layout: row (s-dim) = fk*4 + j, col (d-dim) = fr
    #pragma unroll
    for (int n = 0; n < 4; ++n)
        #pragma unroll
        for (int j = 0; j < 4; ++j)
            atomicAdd(&out[((b * NS_ + wv * 16 + fk * 4 + j) * NH_ + h) * HD_
                           + n * 16 + fr],
                      acc[n][j]);
}

// ---------------------------------------------------------------------------
extern "C" void kernel_launch(void* const* d_in, const int* in_sizes, int n_in,
                              void* d_out, int out_size, void* d_ws, size_t ws_size,
                              hipStream_t stream) {
    const float* H     = (const float*)d_in[0];
    const float* proto = (const float*)d_in[1];
    const float* W     = (const float*)d_in[2];
    float* out = (float*)d_out;
    char*  ws  = (char*)d_ws;

    _Float16*       S  = (_Float16*)ws;                                  // 32 MB
    unsigned short* Hb = (unsigned short*)(ws + (size_t)M_ * N_ * 2);    // 32 MB
    unsigned short* Pb = (unsigned short*)(ws + (size_t)M_ * N_ * 2
                                              + (size_t)M_ * D_ * 2);    // 2 MB
    float* cp   = (float*)((char*)Pb + (size_t)N_ * D_ * 2);             // 2 MB
    float* csuf = cp + (size_t)B_ * NH_ * NCH_ * 64;                     // 2 MB

    hipMemsetAsync(d_out, 0, (size_t)out_size * sizeof(float), stream);

    k_h2bf      <<<2048,              256, 0, stream>>>(H, Hb);
    k_protoproj <<<256,               256, 0, stream>>>(proto, W, Pb);
    k_gemm      <<<(M_/128)*(N_/128), 256, 0, stream>>>(Hb, Pb, S);
    k_cp        <<<256,               256, 0, stream>>>(S, cp);
    k_scan      <<<B_*NH_,            256, 0, stream>>>(cp, csuf);
    k_out_mfma  <<<B_*NH_*16,         256, 0, stream>>>(S, Hb, csuf, out);
}